// Round 1
// baseline (1247.751 us; speedup 1.0000x reference)
//
#include <hip/hip_runtime.h>
#include <math.h>

// Problem constants
#define B_  32
#define S_  2048
#define E_  1024   // 2*HIDDEN
#define A_  512    // ATT
#define H_  512

#define SCHUNK   128
#define NCHUNK   (S_ / SCHUNK)   // 16
#define MTILE    32
#define KT       16
#define NTHREADS 256

// ---------------------------------------------------------------------------
// Kernel A: decoder_att[b][a] = sum_h dh[b][h] * W_dec[h][a] + b_dec[a]
// ---------------------------------------------------------------------------
__global__ __launch_bounds__(256)
void dec_att_kernel(const float* __restrict__ dh,
                    const float* __restrict__ Wdec,
                    const float* __restrict__ bdec,
                    float* __restrict__ dec_att) {
    __shared__ float dhl[H_];
    const int b = blockIdx.x;
    const int t = threadIdx.x;
    for (int i = t; i < H_; i += 256) dhl[i] = dh[b * H_ + i];
    __syncthreads();
    const int a0 = t, a1 = t + 256;
    float acc0 = 0.f, acc1 = 0.f;
    for (int h = 0; h < H_; ++h) {
        const float s = dhl[h];
        acc0 += s * Wdec[h * A_ + a0];
        acc1 += s * Wdec[h * A_ + a1];
    }
    dec_att[b * A_ + a0] = acc0 + bdec[a0];
    dec_att[b * A_ + a1] = acc1 + bdec[a1];
}

// ---------------------------------------------------------------------------
// Kernel B: fused  enc@W_enc -> tanh-score -> online masked softmax -> ctx
// One workgroup per (b, s-chunk of SCHUNK rows). Emits per-chunk partials
// (m, l, ctx[A_]) for flash-style combination in kernel C.
// ---------------------------------------------------------------------------
__global__ __launch_bounds__(NTHREADS, 2)
void chunk_kernel(const float* __restrict__ enc,     // [B,S,E]
                  const int*   __restrict__ masks,   // [B,S]
                  const float* __restrict__ Wenc,    // [E,A]
                  const float* __restrict__ benc,    // [A]
                  const float* __restrict__ Watt,    // [A]
                  const float* __restrict__ batt,    // [1]
                  const float* __restrict__ dec_att, // [B,A]
                  float* __restrict__ pm,            // [B*NCHUNK]
                  float* __restrict__ pl,            // [B*NCHUNK]
                  float* __restrict__ pctx) {        // [B*NCHUNK, A]
    __shared__ float Wt[KT][A_];        // 32 KB   W k-tile
    __shared__ float At[KT][MTILE];     // 2 KB    A k-tile (transposed)
    __shared__ float decl[A_];          // 2 KB
    __shared__ float wattl[A_];         // 2 KB
    __shared__ float bencl[A_];         // 2 KB
    __shared__ float red[4 * A_];       // 8 KB    score parts [32][64] / ctx [4][512]
    __shared__ float score_s[MTILE];
    __shared__ int   mask_s[MTILE];

    const int b     = blockIdx.x / NCHUNK;
    const int chunk = blockIdx.x % NCHUNK;
    const int t  = threadIdx.x;
    const int cg = t & 63;   // owns cols cg*8 .. cg*8+7
    const int rg = t >> 6;   // owns rows rg*8 .. rg*8+7 (within M-tile)

    for (int i = t; i < A_; i += NTHREADS) {
        decl[i]  = dec_att[b * A_ + i];
        wattl[i] = Watt[i];
        bencl[i] = benc[i];
    }
    const float battv = batt[0];

    float m_run = -1e30f, l_run = 0.f;
    float ctx_p[8];
#pragma unroll
    for (int j = 0; j < 8; ++j) ctx_p[j] = 0.f;

    const int s0base = chunk * SCHUNK;
    const int a0 = cg * 8;

    for (int mt = 0; mt < SCHUNK / MTILE; ++mt) {
        const int s0 = s0base + mt * MTILE;
        const float* encB = enc + ((size_t)b * S_ + s0) * E_;

        float acc[8][8];
#pragma unroll
        for (int i = 0; i < 8; ++i)
#pragma unroll
            for (int j = 0; j < 8; ++j) acc[i][j] = 0.f;

        for (int kt = 0; kt < E_ / KT; ++kt) {
            const int k0 = kt * KT;
            // ---- stage W tile: rows k0..k0+15 of Wenc = 8192 contiguous floats
            {
                const float4* wsrc = (const float4*)(Wenc + (size_t)k0 * A_);
                float4* wdst = (float4*)(&Wt[0][0]);
#pragma unroll
                for (int i = 0; i < 8; ++i)
                    wdst[i * NTHREADS + t] = wsrc[i * NTHREADS + t];
            }
            // ---- stage A tile transposed: At[k][r] = enc[b][s0+r][k0+k]
            {
                const int r  = t >> 3;
                const int kk = (t & 7) * 2;
                const float2 v = *(const float2*)(encB + (size_t)r * E_ + k0 + kk);
                At[kk][r]     = v.x;
                At[kk + 1][r] = v.y;
            }
            __syncthreads();
#pragma unroll
            for (int k = 0; k < KT; ++k) {
                const float4 av0 = *(const float4*)(&At[k][rg * 8]);
                const float4 av1 = *(const float4*)(&At[k][rg * 8 + 4]);
                const float4 wv0 = *(const float4*)(&Wt[k][a0]);
                const float4 wv1 = *(const float4*)(&Wt[k][a0 + 4]);
                const float av[8] = {av0.x, av0.y, av0.z, av0.w, av1.x, av1.y, av1.z, av1.w};
                const float wv[8] = {wv0.x, wv0.y, wv0.z, wv0.w, wv1.x, wv1.y, wv1.z, wv1.w};
#pragma unroll
                for (int i = 0; i < 8; ++i)
#pragma unroll
                    for (int j = 0; j < 8; ++j) acc[i][j] += av[i] * wv[j];
            }
            __syncthreads();
        }

        // encoder_att = acc + b_enc  (used by BOTH score and context)
#pragma unroll
        for (int i = 0; i < 8; ++i)
#pragma unroll
            for (int j = 0; j < 8; ++j) acc[i][j] += bencl[a0 + j];

        // per-row score partials: sum_j tanh(ea + da) * w_att
#pragma unroll
        for (int i = 0; i < 8; ++i) {
            float part = 0.f;
#pragma unroll
            for (int j = 0; j < 8; ++j)
                part += tanhf(acc[i][j] + decl[a0 + j]) * wattl[a0 + j];
            red[(rg * 8 + i) * 64 + cg] = part;
        }
        if (t < MTILE) mask_s[t] = masks[(size_t)b * S_ + s0 + t];
        __syncthreads();
        if (t < MTILE) {
            float ssum = 0.f;
            for (int c = 0; c < 64; ++c) ssum += red[t * 64 + c];
            score_s[t] = ssum + battv;
        }
        __syncthreads();

        // ---- online softmax update (computed redundantly, wave-uniform)
        float tile_max = -1e30f;
        for (int r = 0; r < MTILE; ++r)
            if (!mask_s[r]) tile_max = fmaxf(tile_max, score_s[r]);
        const float m_new = fmaxf(m_run, tile_max);
        const float alpha = __expf(m_run - m_new);  // both -1e30 -> exp(0)=1, safe
        float psum = 0.f;
        for (int r = 0; r < MTILE; ++r) {
            const float pr = mask_s[r] ? 0.f : __expf(score_s[r] - m_new);
            psum += pr;
        }
        l_run = l_run * alpha + psum;
        m_run = m_new;
#pragma unroll
        for (int j = 0; j < 8; ++j) ctx_p[j] *= alpha;
#pragma unroll
        for (int i = 0; i < 8; ++i) {
            const int r = rg * 8 + i;
            const float pr = mask_s[r] ? 0.f : __expf(score_s[r] - m_new);
#pragma unroll
            for (int j = 0; j < 8; ++j) ctx_p[j] += pr * acc[i][j];
        }
        __syncthreads();  // protect red/Wt/At/score_s before next tile
    }

    // ---- combine the 4 row-groups' ctx partials, write chunk partials
#pragma unroll
    for (int j = 0; j < 8; ++j) red[rg * A_ + a0 + j] = ctx_p[j];
    __syncthreads();
    const int pc = b * NCHUNK + chunk;
    if (t < 64) {
#pragma unroll
        for (int j = 0; j < 8; ++j) {
            const int a = t * 8 + j;
            pctx[(size_t)pc * A_ + a] =
                red[a] + red[A_ + a] + red[2 * A_ + a] + red[3 * A_ + a];
        }
    }
    if (t == 0) { pm[pc] = m_run; pl[pc] = l_run; }
}

// ---------------------------------------------------------------------------
// Kernel C: merge chunk partials per batch row
// ---------------------------------------------------------------------------
__global__ __launch_bounds__(256)
void combine_kernel(const float* __restrict__ pm,
                    const float* __restrict__ pl,
                    const float* __restrict__ pctx,
                    float* __restrict__ out) {
    const int b = blockIdx.x;
    const int t = threadIdx.x;
    float m_g = -1e30f;
    for (int c = 0; c < NCHUNK; ++c) m_g = fmaxf(m_g, pm[b * NCHUNK + c]);
    float L = 0.f;
    for (int c = 0; c < NCHUNK; ++c)
        L += pl[b * NCHUNK + c] * __expf(pm[b * NCHUNK + c] - m_g);
    const float inv = 1.f / L;
    for (int a = t; a < A_; a += 256) {
        float s = 0.f;
        for (int c = 0; c < NCHUNK; ++c)
            s += pctx[((size_t)b * NCHUNK + c) * A_ + a] *
                 __expf(pm[b * NCHUNK + c] - m_g);
        out[b * A_ + a] = s * inv;
    }
}

// ---------------------------------------------------------------------------
extern "C" void kernel_launch(void* const* d_in, const int* in_sizes, int n_in,
                              void* d_out, int out_size, void* d_ws, size_t ws_size,
                              hipStream_t stream) {
    const float* enc  = (const float*)d_in[0];   // [B,S,2H] fp32
    const float* dh   = (const float*)d_in[1];   // [B,H]    fp32
    const int*   mks  = (const int*)  d_in[2];   // [B,S,1]  bool->int
    const float* Wenc = (const float*)d_in[3];   // [2H,A]
    const float* benc = (const float*)d_in[4];   // [A]
    const float* Wdec = (const float*)d_in[5];   // [H,A]
    const float* bdec = (const float*)d_in[6];   // [A]
    const float* Watt = (const float*)d_in[7];   // [A]
    const float* batt = (const float*)d_in[8];   // [1]
    float* out = (float*)d_out;

    float* ws      = (float*)d_ws;
    float* dec_att = ws;                         // B*A        = 16384
    float* pm      = dec_att + B_ * A_;          // B*NCHUNK   = 512
    float* pl      = pm + B_ * NCHUNK;           // B*NCHUNK   = 512
    float* pctx    = pl + B_ * NCHUNK;           // B*NCHUNK*A = 262144
    (void)in_sizes; (void)n_in; (void)out_size; (void)ws_size;

    dec_att_kernel<<<B_, 256, 0, stream>>>(dh, Wdec, bdec, dec_att);
    chunk_kernel<<<B_ * NCHUNK, NTHREADS, 0, stream>>>(
        enc, mks, Wenc, benc, Watt, batt, dec_att, pm, pl, pctx);
    combine_kernel<<<B_, 256, 0, stream>>>(pm, pl, pctx, out);
}

// Round 2
// 769.458 us; speedup vs baseline: 1.6216x; 1.6216x over previous
//
#include <hip/hip_runtime.h>
#include <math.h>

// Problem constants
#define B_  32
#define S_  2048
#define E_  1024   // 2*HIDDEN
#define A_  512    // ATT
#define H_  512

#define MB   64              // rows (s) per fused block
#define NCH  (S_ / MB)       // 32 chunks per batch row
#define KT   32              // K per MFMA step

typedef __bf16 bf16;
typedef __attribute__((ext_vector_type(8))) __bf16 bf16x8;
typedef __attribute__((ext_vector_type(4))) __bf16 bf16x4;
typedef __attribute__((ext_vector_type(4))) float  f32x4;

typedef const __attribute__((address_space(1))) unsigned int g_u32;
typedef __attribute__((address_space(3))) unsigned int lds_u32;

__device__ __forceinline__ void glds16(const void* g, void* l) {
    __builtin_amdgcn_global_load_lds((g_u32*)g, (lds_u32*)l, 16, 0, 0);
}

// ---------------------------------------------------------------------------
// Kernel W: split W_enc into bf16 hi/lo, transposed -> Wt[a][k]
// ---------------------------------------------------------------------------
__global__ __launch_bounds__(256)
void wsplit_kernel(const float* __restrict__ Wenc,
                   bf16* __restrict__ Whi, bf16* __restrict__ Wlo) {
    const int idx = blockIdx.x * 256 + threadIdx.x;   // over 1024*512
    const int k = idx >> 9;
    const int a = idx & 511;
    const float x = Wenc[idx];
    const bf16 h = (bf16)x;
    const float r = x - (float)h;
    const bf16 l = (bf16)r;
    Whi[(size_t)a * E_ + k] = h;
    Wlo[(size_t)a * E_ + k] = l;
}

// ---------------------------------------------------------------------------
// Kernel A: decoder_att[b][a] = dh[b] @ W_dec + b_dec
// ---------------------------------------------------------------------------
__global__ __launch_bounds__(256)
void dec_att_kernel(const float* __restrict__ dh,
                    const float* __restrict__ Wdec,
                    const float* __restrict__ bdec,
                    float* __restrict__ dec_att) {
    __shared__ float dhl[H_];
    const int b = blockIdx.x;
    const int t = threadIdx.x;
    for (int i = t; i < H_; i += 256) dhl[i] = dh[b * H_ + i];
    __syncthreads();
    const int a0 = t, a1 = t + 256;
    float acc0 = 0.f, acc1 = 0.f;
    for (int h = 0; h < H_; ++h) {
        const float s = dhl[h];
        acc0 += s * Wdec[h * A_ + a0];
        acc1 += s * Wdec[h * A_ + a1];
    }
    dec_att[b * A_ + a0] = acc0 + bdec[a0];
    dec_att[b * A_ + a1] = acc1 + bdec[a1];
}

// ---------------------------------------------------------------------------
// Fused kernel: bf16x2-split MFMA GEMM (64 x 512 x 1024 per block) +
// tanh score + masked online-softmax partials + ctx partials.
// 512 threads = 8 waves; wave w owns cols [w*64, w*64+64), all 64 rows.
// Per wave: 4 m-tiles x 4 n-tiles of 16x16, f32x4 accs (64 VGPRs).
// ---------------------------------------------------------------------------
__global__ __launch_bounds__(512, 4)
void fused_kernel(const float* __restrict__ enc,     // [B,S,E] fp32
                  const int*   __restrict__ masks,   // [B,S]
                  const bf16*  __restrict__ Whi_g,   // [A,E] bf16 (W^T hi)
                  const bf16*  __restrict__ Wlo_g,   // [A,E] bf16 (W^T lo)
                  const float* __restrict__ benc,    // [A]
                  const float* __restrict__ Watt,    // [A]
                  const float* __restrict__ batt,    // [1]
                  const float* __restrict__ dec_att, // [B,A]
                  float* __restrict__ pm,            // [B*NCH]
                  float* __restrict__ pl,            // [B*NCH]
                  float* __restrict__ pctx) {        // [B*NCH, A]
    // ---- LDS ----
    __shared__ union {
        struct {                      // K-loop phase: frag-order W tiles
            bf16 Whi[A_ * KT];        // 32 KB  (32 n-blocks * 512 elems)
            bf16 Wlo[A_ * KT];        // 32 KB
        } w;
        struct {                      // epilogue phase
            float red[MB * 128];      // 32 KB  score partials [64][128]
            float decl[A_];           //  2 KB
            float wattl[A_];          //  2 KB
            float bencl[A_];          //  2 KB
            float redb[512];          //  2 KB
            float red2[A_ * 4];       //  8 KB  ctx partials [col][quad]
        } e;
    } sm;
    __shared__ __align__(16) bf16 Ahi[MB * KT];   // 4 KB, frag-order
    __shared__ __align__(16) bf16 Alo[MB * KT];   // 4 KB
    __shared__ float score_s[MB];
    __shared__ float p_s[MB];
    __shared__ int   mask_s[MB];

    const int t    = threadIdx.x;
    const int wv   = t >> 6;      // wave 0..7
    const int L    = t & 63;      // lane
    const int quad = L >> 4;      // 0..3
    const int colL = L & 15;      // 0..15
    const int b    = blockIdx.x >> 5;
    const int ch   = blockIdx.x & 31;
    const int s0   = ch * MB;

    const float* encB = enc + ((size_t)(b * S_ + s0)) * E_;

    f32x4 acc[4][4];
#pragma unroll
    for (int mt = 0; mt < 4; ++mt)
#pragma unroll
        for (int nt = 0; nt < 4; ++nt) acc[mt][nt] = (f32x4){0.f, 0.f, 0.f, 0.f};

    // A staging decode for this thread (frag-order LDS layout):
    // chunk(16B) index = mt*64 + kb*16 + mloc  -> elem offset = chunk*8
    const int arow  = t >> 3;                  // 0..63
    const int akq   = t & 7;                   // which float4 in the row
    const int a_dst = ((arow >> 4) * 512) + (((akq >> 1) * 16 + (arow & 15)) * 8)
                      + (akq & 1) * 4;         // element offset (bf16)
    const size_t a_src_row = (size_t)arow * E_ + akq * 4;

    for (int kt = 0; kt < E_ / KT; ++kt) {
        const int k0 = kt * KT;
        // prefetch A (global->reg) before the barrier
        const float4 av = *(const float4*)(encB + a_src_row + k0);

        __syncthreads();   // previous iteration's frag reads complete

        // ---- W tiles via async global->LDS (frag-order: lane L -> dst+L*16)
#pragma unroll
        for (int i = 0; i < 4; ++i) {
            const int I = wv * 4 + i;                       // n-block 0..31
            const size_t goff = (size_t)(I * 16 + colL) * E_ + k0 + quad * 8;
            glds16(Whi_g + goff, &sm.w.Whi[I * 512]);
            glds16(Wlo_g + goff, &sm.w.Wlo[I * 512]);
        }

        // ---- A tile: fp32 -> bf16 hi/lo, frag-order
        {
            const bf16 h0 = (bf16)av.x, h1 = (bf16)av.y, h2 = (bf16)av.z, h3 = (bf16)av.w;
            const bf16 l0 = (bf16)(av.x - (float)h0);
            const bf16 l1 = (bf16)(av.y - (float)h1);
            const bf16 l2 = (bf16)(av.z - (float)h2);
            const bf16 l3 = (bf16)(av.w - (float)h3);
            bf16x4 hv; hv[0] = h0; hv[1] = h1; hv[2] = h2; hv[3] = h3;
            bf16x4 lv; lv[0] = l0; lv[1] = l1; lv[2] = l2; lv[3] = l3;
            *(bf16x4*)&Ahi[a_dst] = hv;
            *(bf16x4*)&Alo[a_dst] = lv;
        }

        __syncthreads();   // staging (vmcnt + lgkmcnt) drained

        // ---- fragments + MFMA
        bf16x8 ah[4], al[4];
#pragma unroll
        for (int mt = 0; mt < 4; ++mt) {
            ah[mt] = *(const bf16x8*)&Ahi[mt * 512 + L * 8];
            al[mt] = *(const bf16x8*)&Alo[mt * 512 + L * 8];
        }
#pragma unroll
        for (int nt = 0; nt < 4; ++nt) {
            const int nb = wv * 4 + nt;
            const bf16x8 bh = *(const bf16x8*)&sm.w.Whi[nb * 512 + L * 8];
            const bf16x8 bl = *(const bf16x8*)&sm.w.Wlo[nb * 512 + L * 8];
#pragma unroll
            for (int mt = 0; mt < 4; ++mt) {
                acc[mt][nt] = __builtin_amdgcn_mfma_f32_16x16x32_bf16(ah[mt], bh, acc[mt][nt], 0, 0, 0);
                acc[mt][nt] = __builtin_amdgcn_mfma_f32_16x16x32_bf16(al[mt], bh, acc[mt][nt], 0, 0, 0);
                acc[mt][nt] = __builtin_amdgcn_mfma_f32_16x16x32_bf16(ah[mt], bl, acc[mt][nt], 0, 0, 0);
            }
        }
    }

    __syncthreads();   // K-loop LDS dead; repurpose union for epilogue

    // ---- epilogue tables
    {
        sm.e.decl[t]  = dec_att[b * A_ + t];   // t < 512 == A_
        sm.e.wattl[t] = Watt[t];
        sm.e.bencl[t] = benc[t];
        if (t < MB) mask_s[t] = masks[(size_t)b * S_ + s0 + t];
    }
    __syncthreads();

    // ---- bias + tanh score partials (acc  ->  encoder_att in-register)
    float sp[4][4];
#pragma unroll
    for (int mt = 0; mt < 4; ++mt)
#pragma unroll
        for (int r = 0; r < 4; ++r) sp[mt][r] = 0.f;

#pragma unroll
    for (int nt = 0; nt < 4; ++nt) {
        const int cg = wv * 64 + nt * 16 + colL;
        const float bv  = sm.e.bencl[cg];
        const float dv  = sm.e.decl[cg];
        const float wav = sm.e.wattl[cg];
#pragma unroll
        for (int mt = 0; mt < 4; ++mt)
#pragma unroll
            for (int r = 0; r < 4; ++r) {
                const float ea = acc[mt][nt][r] + bv;
                acc[mt][nt][r] = ea;
                sp[mt][r] += tanhf(ea + dv) * wav;
            }
    }
#pragma unroll
    for (int mt = 0; mt < 4; ++mt)
#pragma unroll
        for (int r = 0; r < 4; ++r) {
            const int row = mt * 16 + quad * 4 + r;
            sm.e.red[row * 128 + wv * 16 + colL] = sp[mt][r];
        }
    __syncthreads();

    // ---- score reduction: 128 contributions per row
    {
        const int r = t >> 3, seg = t & 7;
        float s = 0.f;
#pragma unroll
        for (int j = 0; j < 16; ++j) s += sm.e.red[r * 128 + seg * 16 + j];
        sm.e.redb[r * 8 + seg] = s;
    }
    __syncthreads();
    if (t < MB) {
        float s = 0.f;
#pragma unroll
        for (int j = 0; j < 8; ++j) s += sm.e.redb[t * 8 + j];
        score_s[t] = s + batt[0];
    }
    __syncthreads();

    // ---- masked softmax partials (local max over this block's 64 rows)
    float m_loc = -1e30f;
    for (int r = 0; r < MB; ++r)
        if (!mask_s[r]) m_loc = fmaxf(m_loc, score_s[r]);
    if (t < MB) p_s[t] = mask_s[t] ? 0.f : __expf(score_s[t] - m_loc);
    __syncthreads();

    // ---- ctx partials: sum_r p[r] * encoder_att[r][col]
    float ctxl[4] = {0.f, 0.f, 0.f, 0.f};
#pragma unroll
    for (int mt = 0; mt < 4; ++mt)
#pragma unroll
        for (int r = 0; r < 4; ++r) {
            const float p = p_s[mt * 16 + quad * 4 + r];
#pragma unroll
            for (int nt = 0; nt < 4; ++nt) ctxl[nt] += p * acc[mt][nt][r];
        }
#pragma unroll
    for (int nt = 0; nt < 4; ++nt) {
        const int cg = wv * 64 + nt * 16 + colL;
        sm.e.red2[cg * 4 + quad] = ctxl[nt];
    }
    __syncthreads();

    {   // t < 512 == A_
        const float c = sm.e.red2[t * 4] + sm.e.red2[t * 4 + 1] +
                        sm.e.red2[t * 4 + 2] + sm.e.red2[t * 4 + 3];
        pctx[(size_t)blockIdx.x * A_ + t] = c;
    }
    if (t == 0) {
        float l = 0.f;
        for (int r = 0; r < MB; ++r) l += p_s[r];
        pm[blockIdx.x] = m_loc;
        pl[blockIdx.x] = l;
    }
}

// ---------------------------------------------------------------------------
// Combine: merge NCH chunk partials per batch row
// ---------------------------------------------------------------------------
__global__ __launch_bounds__(512)
void combine_kernel(const float* __restrict__ pm,
                    const float* __restrict__ pl,
                    const float* __restrict__ pctx,
                    float* __restrict__ out) {
    const int b = blockIdx.x;
    const int t = threadIdx.x;
    float m_g = -1e30f;
    for (int c = 0; c < NCH; ++c) m_g = fmaxf(m_g, pm[b * NCH + c]);
    float L = 0.f;
    for (int c = 0; c < NCH; ++c)
        L += pl[b * NCH + c] * __expf(pm[b * NCH + c] - m_g);
    const float inv = 1.f / L;
    // t < 512 == A_
    float s = 0.f;
    for (int c = 0; c < NCH; ++c)
        s += pctx[((size_t)b * NCH + c) * A_ + t] * __expf(pm[b * NCH + c] - m_g);
    out[b * A_ + t] = s * inv;
}

// ---------------------------------------------------------------------------
extern "C" void kernel_launch(void* const* d_in, const int* in_sizes, int n_in,
                              void* d_out, int out_size, void* d_ws, size_t ws_size,
                              hipStream_t stream) {
    const float* enc  = (const float*)d_in[0];   // [B,S,2H] fp32
    const float* dh   = (const float*)d_in[1];   // [B,H]
    const int*   mks  = (const int*)  d_in[2];   // [B,S,1] bool->int
    const float* Wenc = (const float*)d_in[3];   // [2H,A]
    const float* benc = (const float*)d_in[4];   // [A]
    const float* Wdec = (const float*)d_in[5];   // [H,A]
    const float* bdec = (const float*)d_in[6];   // [A]
    const float* Watt = (const float*)d_in[7];   // [A]
    const float* batt = (const float*)d_in[8];   // [1]
    float* out = (float*)d_out;

    float* ws      = (float*)d_ws;
    float* dec_att = ws;                          // 16384 f
    float* pm      = dec_att + B_ * A_;           // 1024 f
    float* pl      = pm + B_ * NCH;               // 1024 f
    float* pctx    = pl + B_ * NCH;               // 524288 f
    bf16*  Whi     = (bf16*)(pctx + B_ * NCH * A_);   // 1 MB
    bf16*  Wlo     = Whi + (size_t)A_ * E_;           // 1 MB
    (void)in_sizes; (void)n_in; (void)out_size; (void)ws_size;

    wsplit_kernel<<<(E_ * A_) / 256, 256, 0, stream>>>(Wenc, Whi, Wlo);
    dec_att_kernel<<<B_, 256, 0, stream>>>(dh, Wdec, bdec, dec_att);
    fused_kernel<<<B_ * NCH, 512, 0, stream>>>(
        enc, mks, Whi, Wlo, benc, Watt, batt, dec_att, pm, pl, pctx);
    combine_kernel<<<B_, 512, 0, stream>>>(pm, pl, pctx, out);
}

// Round 3
// 643.041 us; speedup vs baseline: 1.9404x; 1.1966x over previous
//
#include <hip/hip_runtime.h>
#include <math.h>

// Problem constants
#define B_  32
#define S_  2048
#define E_  1024   // 2*HIDDEN
#define A_  512    // ATT
#define H_  512

#define MB   64              // rows (s) per fused block
#define NCH  (S_ / MB)       // 32 chunks per batch row
#define KT   32              // K per MFMA step

typedef __bf16 bf16;
typedef __attribute__((ext_vector_type(8))) __bf16 bf16x8;
typedef __attribute__((ext_vector_type(4))) __bf16 bf16x4;
typedef __attribute__((ext_vector_type(4))) float  f32x4;

typedef const __attribute__((address_space(1))) unsigned int g_u32;
typedef __attribute__((address_space(3))) unsigned int lds_u32;

__device__ __forceinline__ void glds16(const void* g, void* l) {
    __builtin_amdgcn_global_load_lds((g_u32*)g, (lds_u32*)l, 16, 0, 0);
}

__device__ __forceinline__ float fast_tanh(float x) {
    x = fminf(fmaxf(x, -15.f), 15.f);
    const float e = __expf(2.f * x);
    return (e - 1.f) / (e + 1.f);
}

// ---------------------------------------------------------------------------
// Kernel W: split W_enc into bf16 hi/lo, transposed -> Wt[a][k].
// Also zero-inits dec_att (accumulated via atomics by the next dispatch).
// ---------------------------------------------------------------------------
__global__ __launch_bounds__(256)
void wsplit_kernel(const float* __restrict__ Wenc,
                   bf16* __restrict__ Whi, bf16* __restrict__ Wlo,
                   float* __restrict__ dec_att) {
    const int idx = blockIdx.x * 256 + threadIdx.x;   // over 1024*512
    if (idx < B_ * A_) dec_att[idx] = 0.f;
    const int k = idx >> 9;
    const int a = idx & 511;
    const float x = Wenc[idx];
    const bf16 h = (bf16)x;
    const float r = x - (float)h;
    const bf16 l = (bf16)r;
    Whi[(size_t)a * E_ + k] = h;
    Wlo[(size_t)a * E_ + k] = l;
}

// ---------------------------------------------------------------------------
// Kernel A: decoder_att[b][a] += dh[b][kseg] @ W_dec[kseg][a]  (k-split, atomic)
// grid = 32 b * 8 ksegs = 256 blocks; adds b_dec once (kseg 0).
// ---------------------------------------------------------------------------
__global__ __launch_bounds__(256)
void dec_att_kernel(const float* __restrict__ dh,
                    const float* __restrict__ Wdec,
                    const float* __restrict__ bdec,
                    float* __restrict__ dec_att) {
    __shared__ float dhl[64];
    const int b   = blockIdx.x >> 3;
    const int seg = blockIdx.x & 7;
    const int t   = threadIdx.x;
    if (t < 64) dhl[t] = dh[b * H_ + seg * 64 + t];
    __syncthreads();
    const int a0 = t, a1 = t + 256;
    float acc0 = 0.f, acc1 = 0.f;
    const float* Wrow = Wdec + (size_t)(seg * 64) * A_;
#pragma unroll 8
    for (int h = 0; h < 64; ++h) {
        const float s = dhl[h];
        acc0 += s * Wrow[h * A_ + a0];
        acc1 += s * Wrow[h * A_ + a1];
    }
    if (seg == 0) { acc0 += bdec[a0]; acc1 += bdec[a1]; }
    atomicAdd(&dec_att[b * A_ + a0], acc0);
    atomicAdd(&dec_att[b * A_ + a1], acc1);
}

// ---------------------------------------------------------------------------
// Fused kernel: bf16x2-split MFMA GEMM (64 x 512 x 1024 per block) +
// tanh score + masked softmax partials + ctx partials.
// 512 threads = 8 waves; wave w owns cols [w*64, w*64+64), all 64 rows.
// Two-pass K-step keeps frag live-set at bb[4]+ah+al = 24 VGPRs (anti-spill).
// ---------------------------------------------------------------------------
__global__ __launch_bounds__(512, 4)
void fused_kernel(const float* __restrict__ enc,     // [B,S,E] fp32
                  const int*   __restrict__ masks,   // [B,S]
                  const bf16*  __restrict__ Whi_g,   // [A,E] bf16 (W^T hi)
                  const bf16*  __restrict__ Wlo_g,   // [A,E] bf16 (W^T lo)
                  const float* __restrict__ benc,    // [A]
                  const float* __restrict__ Watt,    // [A]
                  const float* __restrict__ batt,    // [1]
                  const float* __restrict__ dec_att, // [B,A]
                  float* __restrict__ pm,            // [B*NCH]
                  float* __restrict__ pl,            // [B*NCH]
                  float* __restrict__ pctx) {        // [B*NCH, A]
    __shared__ union {
        struct {                      // K-loop phase: frag-order W tiles
            bf16 Whi[A_ * KT];        // 32 KB
            bf16 Wlo[A_ * KT];        // 32 KB
        } w;
        struct {                      // epilogue phase
            float red[MB * 128];      // 32 KB  score partials [64][128]
            float decl[A_];           //  2 KB
            float wattl[A_];          //  2 KB
            float bencl[A_];          //  2 KB
            float redb[512];          //  2 KB
            float red2[A_ * 4];       //  8 KB  ctx partials [col][quad]
        } e;
    } sm;
    __shared__ __align__(16) bf16 Ahi[MB * KT];   // 4 KB, frag-order
    __shared__ __align__(16) bf16 Alo[MB * KT];   // 4 KB
    __shared__ float score_s[MB];
    __shared__ float p_s[MB];
    __shared__ int   mask_s[MB];

    const int t    = threadIdx.x;
    const int wv   = t >> 6;      // wave 0..7
    const int L    = t & 63;      // lane
    const int quad = L >> 4;      // 0..3
    const int colL = L & 15;      // 0..15
    const int b    = blockIdx.x >> 5;
    const int ch   = blockIdx.x & 31;
    const int s0   = ch * MB;

    const float* encB = enc + ((size_t)(b * S_ + s0)) * E_;

    f32x4 acc[4][4];
#pragma unroll
    for (int mt = 0; mt < 4; ++mt)
#pragma unroll
        for (int nt = 0; nt < 4; ++nt) acc[mt][nt] = (f32x4){0.f, 0.f, 0.f, 0.f};

    // A staging decode (frag-order LDS layout):
    const int arow  = t >> 3;                  // 0..63
    const int akq   = t & 7;                   // which float4 in the row
    const int a_dst = ((arow >> 4) * 512) + (((akq >> 1) * 16 + (arow & 15)) * 8)
                      + (akq & 1) * 4;         // element offset (bf16)
    const size_t a_src_row = (size_t)arow * E_ + akq * 4;

    for (int kt = 0; kt < E_ / KT; ++kt) {
        const int k0 = kt * KT;
        // prefetch A (global->reg) before the barrier
        const float4 av = *(const float4*)(encB + a_src_row + k0);

        __syncthreads();   // previous iteration's frag reads complete

        // ---- W tiles via async global->LDS (frag-order: lane L -> dst+L*16)
#pragma unroll
        for (int i = 0; i < 4; ++i) {
            const int I = wv * 4 + i;                       // n-block 0..31
            const size_t goff = (size_t)(I * 16 + colL) * E_ + k0 + quad * 8;
            glds16(Whi_g + goff, &sm.w.Whi[I * 512]);
            glds16(Wlo_g + goff, &sm.w.Wlo[I * 512]);
        }

        // ---- A tile: fp32 -> bf16 hi/lo, frag-order
        {
            const bf16 h0 = (bf16)av.x, h1 = (bf16)av.y, h2 = (bf16)av.z, h3 = (bf16)av.w;
            const bf16 l0 = (bf16)(av.x - (float)h0);
            const bf16 l1 = (bf16)(av.y - (float)h1);
            const bf16 l2 = (bf16)(av.z - (float)h2);
            const bf16 l3 = (bf16)(av.w - (float)h3);
            bf16x4 hv; hv[0] = h0; hv[1] = h1; hv[2] = h2; hv[3] = h3;
            bf16x4 lv; lv[0] = l0; lv[1] = l1; lv[2] = l2; lv[3] = l3;
            *(bf16x4*)&Ahi[a_dst] = hv;
            *(bf16x4*)&Alo[a_dst] = lv;
        }

        __syncthreads();   // staging (vmcnt + lgkmcnt) drained

        // ---- pass 1: B-hi resident; terms ah*bh + al*bh
        {
            bf16x8 bb[4];
#pragma unroll
            for (int nt = 0; nt < 4; ++nt)
                bb[nt] = *(const bf16x8*)&sm.w.Whi[(wv * 4 + nt) * 512 + L * 8];
#pragma unroll
            for (int mt = 0; mt < 4; ++mt) {
                const bf16x8 ah = *(const bf16x8*)&Ahi[mt * 512 + L * 8];
                const bf16x8 al = *(const bf16x8*)&Alo[mt * 512 + L * 8];
#pragma unroll
                for (int nt = 0; nt < 4; ++nt) {
                    acc[mt][nt] = __builtin_amdgcn_mfma_f32_16x16x32_bf16(ah, bb[nt], acc[mt][nt], 0, 0, 0);
                    acc[mt][nt] = __builtin_amdgcn_mfma_f32_16x16x32_bf16(al, bb[nt], acc[mt][nt], 0, 0, 0);
                }
            }
        }
        // ---- pass 2: B-lo resident; term ah*bl
        {
            bf16x8 bb[4];
#pragma unroll
            for (int nt = 0; nt < 4; ++nt)
                bb[nt] = *(const bf16x8*)&sm.w.Wlo[(wv * 4 + nt) * 512 + L * 8];
#pragma unroll
            for (int mt = 0; mt < 4; ++mt) {
                const bf16x8 ah = *(const bf16x8*)&Ahi[mt * 512 + L * 8];
#pragma unroll
                for (int nt = 0; nt < 4; ++nt)
                    acc[mt][nt] = __builtin_amdgcn_mfma_f32_16x16x32_bf16(ah, bb[nt], acc[mt][nt], 0, 0, 0);
            }
        }
    }

    __syncthreads();   // K-loop LDS dead; repurpose union for epilogue

    // ---- epilogue tables
    {
        sm.e.decl[t]  = dec_att[b * A_ + t];   // t < 512 == A_
        sm.e.wattl[t] = Watt[t];
        sm.e.bencl[t] = benc[t];
        if (t < MB) mask_s[t] = masks[(size_t)b * S_ + s0 + t];
    }
    __syncthreads();

    // ---- bias + tanh score partials (acc -> encoder_att in-register)
    float sp[4][4];
#pragma unroll
    for (int mt = 0; mt < 4; ++mt)
#pragma unroll
        for (int r = 0; r < 4; ++r) sp[mt][r] = 0.f;

#pragma unroll
    for (int nt = 0; nt < 4; ++nt) {
        const int cg = wv * 64 + nt * 16 + colL;
        const float bv  = sm.e.bencl[cg];
        const float dv  = sm.e.decl[cg];
        const float wav = sm.e.wattl[cg];
#pragma unroll
        for (int mt = 0; mt < 4; ++mt)
#pragma unroll
            for (int r = 0; r < 4; ++r) {
                const float ea = acc[mt][nt][r] + bv;
                acc[mt][nt][r] = ea;
                sp[mt][r] += fast_tanh(ea + dv) * wav;
            }
    }
#pragma unroll
    for (int mt = 0; mt < 4; ++mt)
#pragma unroll
        for (int r = 0; r < 4; ++r) {
            const int row = mt * 16 + quad * 4 + r;
            sm.e.red[row * 128 + wv * 16 + colL] = sp[mt][r];
        }
    __syncthreads();

    // ---- score reduction: 128 contributions per row
    {
        const int r = t >> 3, seg = t & 7;
        float s = 0.f;
#pragma unroll
        for (int j = 0; j < 16; ++j) s += sm.e.red[r * 128 + seg * 16 + j];
        sm.e.redb[r * 8 + seg] = s;
    }
    __syncthreads();
    if (t < MB) {
        float s = 0.f;
#pragma unroll
        for (int j = 0; j < 8; ++j) s += sm.e.redb[t * 8 + j];
        score_s[t] = s + batt[0];
    }
    __syncthreads();

    // ---- masked softmax partials (local max over this block's 64 rows)
    float m_loc = -1e30f;
    for (int r = 0; r < MB; ++r)
        if (!mask_s[r]) m_loc = fmaxf(m_loc, score_s[r]);
    if (t < MB) p_s[t] = mask_s[t] ? 0.f : __expf(score_s[t] - m_loc);
    __syncthreads();

    // ---- ctx partials: sum_r p[r] * encoder_att[r][col]
    float ctxl[4] = {0.f, 0.f, 0.f, 0.f};
#pragma unroll
    for (int mt = 0; mt < 4; ++mt)
#pragma unroll
        for (int r = 0; r < 4; ++r) {
            const float p = p_s[mt * 16 + quad * 4 + r];
#pragma unroll
            for (int nt = 0; nt < 4; ++nt) ctxl[nt] += p * acc[mt][nt][r];
        }
#pragma unroll
    for (int nt = 0; nt < 4; ++nt) {
        const int cg = wv * 64 + nt * 16 + colL;
        sm.e.red2[cg * 4 + quad] = ctxl[nt];
    }
    __syncthreads();

    {   // t < 512 == A_
        const float c = sm.e.red2[t * 4] + sm.e.red2[t * 4 + 1] +
                        sm.e.red2[t * 4 + 2] + sm.e.red2[t * 4 + 3];
        pctx[(size_t)blockIdx.x * A_ + t] = c;
    }
    if (t == 0) {
        float l = 0.f;
        for (int r = 0; r < MB; ++r) l += p_s[r];
        pm[blockIdx.x] = m_loc;
        pl[blockIdx.x] = l;
    }
}

// ---------------------------------------------------------------------------
// Combine: merge NCH chunk partials per batch row
// ---------------------------------------------------------------------------
__global__ __launch_bounds__(512)
void combine_kernel(const float* __restrict__ pm,
                    const float* __restrict__ pl,
                    const float* __restrict__ pctx,
                    float* __restrict__ out) {
    const int b = blockIdx.x;
    const int t = threadIdx.x;
    float m_g = -1e30f;
    for (int c = 0; c < NCH; ++c) m_g = fmaxf(m_g, pm[b * NCH + c]);
    float L = 0.f;
    for (int c = 0; c < NCH; ++c)
        L += pl[b * NCH + c] * __expf(pm[b * NCH + c] - m_g);
    const float inv = 1.f / L;
    float s = 0.f;
    for (int c = 0; c < NCH; ++c)
        s += pctx[((size_t)b * NCH + c) * A_ + t] * __expf(pm[b * NCH + c] - m_g);
    out[b * A_ + t] = s * inv;
}

// ---------------------------------------------------------------------------
extern "C" void kernel_launch(void* const* d_in, const int* in_sizes, int n_in,
                              void* d_out, int out_size, void* d_ws, size_t ws_size,
                              hipStream_t stream) {
    const float* enc  = (const float*)d_in[0];   // [B,S,2H] fp32
    const float* dh   = (const float*)d_in[1];   // [B,H]
    const int*   mks  = (const int*)  d_in[2];   // [B,S,1] bool->int
    const float* Wenc = (const float*)d_in[3];   // [2H,A]
    const float* benc = (const float*)d_in[4];   // [A]
    const float* Wdec = (const float*)d_in[5];   // [H,A]
    const float* bdec = (const float*)d_in[6];   // [A]
    const float* Watt = (const float*)d_in[7];   // [A]
    const float* batt = (const float*)d_in[8];   // [1]
    float* out = (float*)d_out;

    float* ws      = (float*)d_ws;
    float* dec_att = ws;                          // 16384 f
    float* pm      = dec_att + B_ * A_;           // 1024 f
    float* pl      = pm + B_ * NCH;               // 1024 f
    float* pctx    = pl + B_ * NCH;               // 524288 f
    bf16*  Whi     = (bf16*)(pctx + B_ * NCH * A_);   // 1 MB
    bf16*  Wlo     = Whi + (size_t)A_ * E_;           // 1 MB
    (void)in_sizes; (void)n_in; (void)out_size; (void)ws_size;

    wsplit_kernel<<<(E_ * A_) / 256, 256, 0, stream>>>(Wenc, Whi, Wlo, dec_att);
    dec_att_kernel<<<B_ * 8, 256, 0, stream>>>(dh, Wdec, bdec, dec_att);
    fused_kernel<<<B_ * NCH, 512, 0, stream>>>(
        enc, mks, Whi, Wlo, benc, Watt, batt, dec_att, pm, pl, pctx);
    combine_kernel<<<B_, 512, 0, stream>>>(pm, pl, pctx, out);
}

// Round 4
// 581.438 us; speedup vs baseline: 2.1460x; 1.1059x over previous
//
#include <hip/hip_runtime.h>
#include <math.h>

// Problem constants
#define B_  32
#define S_  2048
#define E_  1024   // 2*HIDDEN
#define A_  512    // ATT
#define H_  512

#define MB   128             // rows (s) per fused block
#define NCH  (S_ / MB)       // 16 chunks per batch row
#define KT   32              // K per MFMA step
#define NK   (E_ / KT)       // 32 K-iterations

typedef __bf16 bf16;
typedef __attribute__((ext_vector_type(8))) __bf16 bf16x8;
typedef __attribute__((ext_vector_type(4))) float  f32x4;

typedef const __attribute__((address_space(1))) unsigned int g_u32;
typedef __attribute__((address_space(3))) unsigned int lds_u32;

__device__ __forceinline__ void glds16(const void* g, void* l) {
    __builtin_amdgcn_global_load_lds((g_u32*)g, (lds_u32*)l, 16, 0, 0);
}

__device__ __forceinline__ float fast_tanh(float x) {
    x = fminf(fmaxf(x, -15.f), 15.f);
    const float e = __expf(2.f * x);
    return (e - 1.f) / (e + 1.f);
}

// ---------------------------------------------------------------------------
// Kernel W: split W_enc into bf16 hi/lo, TRANSPOSED via LDS tile so both the
// fp32 reads and the bf16 writes are contiguous. Grid: 16 k-tiles x 8 a-tiles.
// Also zero-inits dec_att (accumulated by the next dispatch via atomics).
// ---------------------------------------------------------------------------
__global__ __launch_bounds__(256)
void wsplit_kernel(const float* __restrict__ Wenc,
                   bf16* __restrict__ Whi, bf16* __restrict__ Wlo,
                   float* __restrict__ dec_att) {
    __shared__ float tile[64][65];
    const int t  = threadIdx.x;
    const int kb = blockIdx.x >> 3;      // 0..15
    const int ab = blockIdx.x & 7;       // 0..7
    const int k0 = kb * 64, a0 = ab * 64;

    const int di = blockIdx.x * 256 + t;     // 128*256 = 32768 >= 16384
    if (di < B_ * A_) dec_att[di] = 0.f;

    // load 64x64 fp32 tile, coalesced (8 rows per pass)
#pragma unroll
    for (int p = 0; p < 8; ++p) {
        const int kk = p * 8 + (t >> 5);
        const int aa = (t & 31) * 2;
        const float2 v = *(const float2*)&Wenc[(size_t)(k0 + kk) * A_ + a0 + aa];
        tile[kk][aa]     = v.x;
        tile[kk][aa + 1] = v.y;
    }
    __syncthreads();

    // write transposed: thread -> (a-row aa, 16 consecutive k)
    const int aa  = t >> 2;
    const int kk0 = (t & 3) * 16;
    bf16x8 hv0, hv1, lv0, lv1;
#pragma unroll
    for (int j = 0; j < 16; ++j) {
        const float x = tile[kk0 + j][aa];
        const bf16 h = (bf16)x;
        const bf16 l = (bf16)(x - (float)h);
        if (j < 8) { hv0[j] = h; lv0[j] = l; }
        else       { hv1[j - 8] = h; lv1[j - 8] = l; }
    }
    bf16* dh_ = Whi + (size_t)(a0 + aa) * E_ + k0 + kk0;
    bf16* dl_ = Wlo + (size_t)(a0 + aa) * E_ + k0 + kk0;
    *(bf16x8*)dh_ = hv0; *((bf16x8*)dh_ + 1) = hv1;
    *(bf16x8*)dl_ = lv0; *((bf16x8*)dl_ + 1) = lv1;
}

// ---------------------------------------------------------------------------
// Kernel A: decoder_att[b][a] += dh[b][kseg] @ W_dec[kseg][a]  (k-split, atomic)
// ---------------------------------------------------------------------------
__global__ __launch_bounds__(256)
void dec_att_kernel(const float* __restrict__ dh,
                    const float* __restrict__ Wdec,
                    const float* __restrict__ bdec,
                    float* __restrict__ dec_att) {
    __shared__ float dhl[64];
    const int b   = blockIdx.x >> 3;
    const int seg = blockIdx.x & 7;
    const int t   = threadIdx.x;
    if (t < 64) dhl[t] = dh[b * H_ + seg * 64 + t];
    __syncthreads();
    const int a0 = t, a1 = t + 256;
    float acc0 = 0.f, acc1 = 0.f;
    const float* Wrow = Wdec + (size_t)(seg * 64) * A_;
#pragma unroll 8
    for (int h = 0; h < 64; ++h) {
        const float s = dhl[h];
        acc0 += s * Wrow[h * A_ + a0];
        acc1 += s * Wrow[h * A_ + a1];
    }
    if (seg == 0) { acc0 += bdec[a0]; acc1 += bdec[a1]; }
    atomicAdd(&dec_att[b * A_ + a0], acc0);
    atomicAdd(&dec_att[b * A_ + a1], acc1);
}

// ---------------------------------------------------------------------------
// Fused kernel: bf16x2-split MFMA GEMM (128 x 512 x 1024 per block) +
// tanh score + masked softmax partials + ctx partials.
// 512 threads = 8 waves; wave w owns cols [w*64, w*64+64), all 128 rows.
// One-pass K-step: bh[4]+bl[4]+ah+al live; acc 8x4 f32x4 (128 VGPRs).
// 1 block/CU (LDS ~92 KB), 256-VGPR budget -> no spill.
// ---------------------------------------------------------------------------
__global__ __launch_bounds__(512, 2)
void fused_kernel(const float* __restrict__ enc,     // [B,S,E] fp32
                  const int*   __restrict__ masks,   // [B,S]
                  const bf16*  __restrict__ Whi_g,   // [A,E] bf16 (W^T hi)
                  const bf16*  __restrict__ Wlo_g,   // [A,E] bf16 (W^T lo)
                  const float* __restrict__ benc,    // [A]
                  const float* __restrict__ Watt,    // [A]
                  const float* __restrict__ batt,    // [1]
                  const float* __restrict__ dec_att, // [B,A]
                  float* __restrict__ pm,            // [B*NCH]
                  float* __restrict__ pl,            // [B*NCH]
                  float* __restrict__ pctx) {        // [B*NCH, A]
    __shared__ __align__(16) bf16 Whi_s[A_ * KT];   // 32 KB, frag-order
    __shared__ __align__(16) bf16 Wlo_s[A_ * KT];   // 32 KB
    __shared__ __align__(16) bf16 Ahi_s[MB * KT];   //  8 KB, frag-order+swizzle
    __shared__ __align__(16) bf16 Alo_s[MB * KT];   //  8 KB
    __shared__ float decl[A_], wattl[A_], bencl[A_]; // 6 KB
    __shared__ float red[MB * 8];                    // 4 KB score partials
    __shared__ float score_s[MB], p_s[MB];
    __shared__ int   mask_s[MB];

    const int t    = threadIdx.x;
    const int wv   = t >> 6;      // wave 0..7
    const int L    = t & 63;      // lane
    const int quad = L >> 4;      // 0..3
    const int colL = L & 15;      // 0..15
    const int b    = blockIdx.x >> 4;
    const int ch   = blockIdx.x & 15;
    const int s0   = ch * MB;

    const float* encB = enc + ((size_t)(b * S_ + s0)) * E_;

    f32x4 acc[8][4];
#pragma unroll
    for (int mt = 0; mt < 8; ++mt)
#pragma unroll
        for (int nt = 0; nt < 4; ++nt) acc[mt][nt] = (f32x4){0.f, 0.f, 0.f, 0.f};

    // ---- A staging: thread t -> row t>>2, k-quad t&3 (8 consecutive k)
    const int arow = t >> 2;
    const int akq  = t & 3;
    const int a_wr = ((arow >> 4) * 512) + akq * 128 +
                     (((arow & 15) ^ (akq << 2)) * 8);     // swizzled elem off
    const float* aptr = encB + (size_t)arow * E_ + akq * 8;
    // frag read offset for this lane (k-quad = L>>4, row-in-tile = L&15)
    const int a_rd = quad * 128 + (((L & 15) ^ (quad << 2)) * 8);

    float4 cvA = *(const float4*)(aptr);
    float4 cvB = *(const float4*)(aptr + 4);

    for (int kt = 0; kt < NK; ++kt) {
        const int k0 = kt * KT;
        __syncthreads();   // (1) previous iter's frag reads complete

        // ---- W tiles via async global->LDS (frag-order)
#pragma unroll
        for (int i = 0; i < 4; ++i) {
            const int I = wv * 4 + i;                       // n-block 0..31
            const size_t goff = (size_t)(I * 16 + colL) * E_ + k0 + quad * 8;
            glds16(Whi_g + goff, &Whi_s[I * 512]);
            glds16(Wlo_g + goff, &Wlo_s[I * 512]);
        }

        // ---- A tile: fp32 -> bf16 hi/lo, swizzled frag-order (16B stores)
        {
            const float xs[8] = {cvA.x, cvA.y, cvA.z, cvA.w,
                                 cvB.x, cvB.y, cvB.z, cvB.w};
            bf16x8 hv, lv;
#pragma unroll
            for (int j = 0; j < 8; ++j) {
                const bf16 h = (bf16)xs[j];
                hv[j] = h;
                lv[j] = (bf16)(xs[j] - (float)h);
            }
            *(bf16x8*)&Ahi_s[a_wr] = hv;
            *(bf16x8*)&Alo_s[a_wr] = lv;
        }

        __syncthreads();   // (2) staging drained

        // ---- prefetch A for next iter (hides HBM latency under MFMA block)
        if (kt + 1 < NK) {
            const float* np = aptr + (kt + 1) * KT;
            cvA = *(const float4*)(np);
            cvB = *(const float4*)(np + 4);
        }

        // ---- fragments + MFMA (one pass, all B frags resident)
        bf16x8 bh[4], bl[4];
#pragma unroll
        for (int nt = 0; nt < 4; ++nt) {
            bh[nt] = *(const bf16x8*)&Whi_s[(wv * 4 + nt) * 512 + L * 8];
            bl[nt] = *(const bf16x8*)&Wlo_s[(wv * 4 + nt) * 512 + L * 8];
        }
#pragma unroll
        for (int mt = 0; mt < 8; ++mt) {
            const bf16x8 ah = *(const bf16x8*)&Ahi_s[mt * 512 + a_rd];
            const bf16x8 al = *(const bf16x8*)&Alo_s[mt * 512 + a_rd];
#pragma unroll
            for (int nt = 0; nt < 4; ++nt) {
                acc[mt][nt] = __builtin_amdgcn_mfma_f32_16x16x32_bf16(ah, bh[nt], acc[mt][nt], 0, 0, 0);
                acc[mt][nt] = __builtin_amdgcn_mfma_f32_16x16x32_bf16(al, bh[nt], acc[mt][nt], 0, 0, 0);
                acc[mt][nt] = __builtin_amdgcn_mfma_f32_16x16x32_bf16(ah, bl[nt], acc[mt][nt], 0, 0, 0);
            }
        }
    }

    // ---- epilogue tables
    decl[t < A_ ? t : 0]  = dec_att[b * A_ + (t < A_ ? t : 0)];
    wattl[t] = Watt[t];     // t < 512 == A_
    bencl[t] = benc[t];
    if (t < MB) mask_s[t] = masks[(size_t)b * S_ + s0 + t];
    __syncthreads();

    // ---- bias + tanh score partials (acc -> encoder_att in-register)
    float sp[8][4];
#pragma unroll
    for (int mt = 0; mt < 8; ++mt)
#pragma unroll
        for (int r = 0; r < 4; ++r) sp[mt][r] = 0.f;

#pragma unroll
    for (int nt = 0; nt < 4; ++nt) {
        const int cg = wv * 64 + nt * 16 + colL;
        const float bv  = bencl[cg];
        const float dv  = decl[cg];
        const float wav = wattl[cg];
#pragma unroll
        for (int mt = 0; mt < 8; ++mt)
#pragma unroll
            for (int r = 0; r < 4; ++r) {
                const float ea = acc[mt][nt][r] + bv;
                acc[mt][nt][r] = ea;
                sp[mt][r] += fast_tanh(ea + dv) * wav;
            }
    }
    // shuffle-reduce over colL (16 lanes, same quad)
#pragma unroll
    for (int d = 1; d < 16; d <<= 1)
#pragma unroll
        for (int mt = 0; mt < 8; ++mt)
#pragma unroll
            for (int r = 0; r < 4; ++r)
                sp[mt][r] += __shfl_xor(sp[mt][r], d);
    if (colL == 0) {
#pragma unroll
        for (int mt = 0; mt < 8; ++mt)
#pragma unroll
            for (int r = 0; r < 4; ++r)
                red[(mt * 16 + quad * 4 + r) * 8 + wv] = sp[mt][r];
    }
    __syncthreads();

    if (t < MB) {
        float s = 0.f;
#pragma unroll
        for (int j = 0; j < 8; ++j) s += red[t * 8 + j];
        score_s[t] = s + batt[0];
    }
    __syncthreads();

    // ---- masked softmax partials (local max over the block's 128 rows)
    float m_loc = -1e30f;
    for (int r = 0; r < MB; ++r)
        if (!mask_s[r]) m_loc = fmaxf(m_loc, score_s[r]);
    if (t < MB) p_s[t] = mask_s[t] ? 0.f : __expf(score_s[t] - m_loc);
    __syncthreads();

    // ---- ctx partials: sum_r p[r] * encoder_att[r][col]
    float ctxl[4] = {0.f, 0.f, 0.f, 0.f};
#pragma unroll
    for (int mt = 0; mt < 8; ++mt)
#pragma unroll
        for (int r = 0; r < 4; ++r) {
            const float p = p_s[mt * 16 + quad * 4 + r];
#pragma unroll
            for (int nt = 0; nt < 4; ++nt) ctxl[nt] += p * acc[mt][nt][r];
        }
    // reduce over quad (shfl xor 16, 32), then quad==0 lanes own unique cols
#pragma unroll
    for (int nt = 0; nt < 4; ++nt) {
        ctxl[nt] += __shfl_xor(ctxl[nt], 16);
        ctxl[nt] += __shfl_xor(ctxl[nt], 32);
    }
    if (quad == 0) {
#pragma unroll
        for (int nt = 0; nt < 4; ++nt)
            pctx[(size_t)blockIdx.x * A_ + wv * 64 + nt * 16 + colL] = ctxl[nt];
    }
    if (t == 0) {
        float l = 0.f;
        for (int r = 0; r < MB; ++r) l += p_s[r];
        pm[blockIdx.x] = m_loc;
        pl[blockIdx.x] = l;
    }
}

// ---------------------------------------------------------------------------
// Combine: merge NCH chunk partials per batch row
// ---------------------------------------------------------------------------
__global__ __launch_bounds__(512)
void combine_kernel(const float* __restrict__ pm,
                    const float* __restrict__ pl,
                    const float* __restrict__ pctx,
                    float* __restrict__ out) {
    const int b = blockIdx.x;
    const int t = threadIdx.x;
    float m_g = -1e30f;
    for (int c = 0; c < NCH; ++c) m_g = fmaxf(m_g, pm[b * NCH + c]);
    float L = 0.f;
    for (int c = 0; c < NCH; ++c)
        L += pl[b * NCH + c] * __expf(pm[b * NCH + c] - m_g);
    const float inv = 1.f / L;
    float s = 0.f;
    for (int c = 0; c < NCH; ++c)
        s += pctx[((size_t)b * NCH + c) * A_ + t] * __expf(pm[b * NCH + c] - m_g);
    out[b * A_ + t] = s * inv;
}

// ---------------------------------------------------------------------------
extern "C" void kernel_launch(void* const* d_in, const int* in_sizes, int n_in,
                              void* d_out, int out_size, void* d_ws, size_t ws_size,
                              hipStream_t stream) {
    const float* enc  = (const float*)d_in[0];   // [B,S,2H] fp32
    const float* dh   = (const float*)d_in[1];   // [B,H]
    const int*   mks  = (const int*)  d_in[2];   // [B,S,1] bool->int
    const float* Wenc = (const float*)d_in[3];   // [2H,A]
    const float* benc = (const float*)d_in[4];   // [A]
    const float* Wdec = (const float*)d_in[5];   // [H,A]
    const float* bdec = (const float*)d_in[6];   // [A]
    const float* Watt = (const float*)d_in[7];   // [A]
    const float* batt = (const float*)d_in[8];   // [1]
    float* out = (float*)d_out;

    float* ws      = (float*)d_ws;
    float* dec_att = ws;                          // 16384 f
    float* pm      = dec_att + B_ * A_;           // 512 f
    float* pl      = pm + B_ * NCH;               // 512 f
    float* pctx    = pl + B_ * NCH;               // 262144 f
    bf16*  Whi     = (bf16*)(pctx + B_ * NCH * A_);   // 1 MB
    bf16*  Wlo     = Whi + (size_t)A_ * E_;           // 1 MB
    (void)in_sizes; (void)n_in; (void)out_size; (void)ws_size;

    wsplit_kernel<<<128, 256, 0, stream>>>(Wenc, Whi, Wlo, dec_att);
    dec_att_kernel<<<B_ * 8, 256, 0, stream>>>(dh, Wdec, bdec, dec_att);
    fused_kernel<<<B_ * NCH, 512, 0, stream>>>(
        enc, mks, Whi, Wlo, benc, Watt, batt, dec_att, pm, pl, pctx);
    combine_kernel<<<B_, 512, 0, stream>>>(pm, pl, pctx, out);
}

// Round 5
// 523.429 us; speedup vs baseline: 2.3838x; 1.1108x over previous
//
#include <hip/hip_runtime.h>
#include <math.h>

// Problem constants
#define B_  32
#define S_  2048
#define E_  1024   // 2*HIDDEN
#define A_  512    // ATT
#define H_  512

#define MB   128             // rows (s) per fused block
#define NCH  (S_ / MB)       // 16 chunks per batch row
#define KT   32              // K per MFMA step
#define NK   (E_ / KT)       // 32 K-iterations

typedef __bf16 bf16;
typedef __attribute__((ext_vector_type(8))) __bf16 bf16x8;
typedef __attribute__((ext_vector_type(4))) float  f32x4;

typedef const __attribute__((address_space(1))) unsigned int g_u32;
typedef __attribute__((address_space(3))) unsigned int lds_u32;

__device__ __forceinline__ void glds16(const void* g, void* l) {
    __builtin_amdgcn_global_load_lds((g_u32*)g, (lds_u32*)l, 16, 0, 0);
}

__device__ __forceinline__ float fast_tanh(float x) {
    x = fminf(fmaxf(x, -15.f), 15.f);
    const float e = __expf(2.f * x);
    return (e - 1.f) / (e + 1.f);
}

// ---------------------------------------------------------------------------
// prep kernel: blocks 0..127  : split W_enc into bf16 hi/lo, transposed [a][k]
//              blocks 128..383: dec_att k-split partials dp[seg][b][a]
// ---------------------------------------------------------------------------
__global__ __launch_bounds__(256)
void prep_kernel(const float* __restrict__ Wenc,
                 const float* __restrict__ dh,
                 const float* __restrict__ Wdec,
                 const float* __restrict__ bdec,
                 bf16* __restrict__ Whi, bf16* __restrict__ Wlo,
                 float* __restrict__ dp) {
    const int t = threadIdx.x;
    if (blockIdx.x < 128) {
        __shared__ float tile[64][65];
        const int kb = blockIdx.x >> 3;      // 0..15
        const int ab = blockIdx.x & 7;       // 0..7
        const int k0 = kb * 64, a0 = ab * 64;
#pragma unroll
        for (int p = 0; p < 8; ++p) {
            const int kk = p * 8 + (t >> 5);
            const int aa = (t & 31) * 2;
            const float2 v = *(const float2*)&Wenc[(size_t)(k0 + kk) * A_ + a0 + aa];
            tile[kk][aa]     = v.x;
            tile[kk][aa + 1] = v.y;
        }
        __syncthreads();
        const int aa  = t >> 2;
        const int kk0 = (t & 3) * 16;
        bf16x8 hv0, hv1, lv0, lv1;
#pragma unroll
        for (int j = 0; j < 16; ++j) {
            const float x = tile[kk0 + j][aa];
            const bf16 h = (bf16)x;
            const bf16 l = (bf16)(x - (float)h);
            if (j < 8) { hv0[j] = h; lv0[j] = l; }
            else       { hv1[j - 8] = h; lv1[j - 8] = l; }
        }
        bf16* dh_ = Whi + (size_t)(a0 + aa) * E_ + k0 + kk0;
        bf16* dl_ = Wlo + (size_t)(a0 + aa) * E_ + k0 + kk0;
        *(bf16x8*)dh_ = hv0; *((bf16x8*)dh_ + 1) = hv1;
        *(bf16x8*)dl_ = lv0; *((bf16x8*)dl_ + 1) = lv1;
    } else {
        __shared__ float dhl[64];
        const int idx = blockIdx.x - 128;
        const int b   = idx >> 3;
        const int seg = idx & 7;
        if (t < 64) dhl[t] = dh[b * H_ + seg * 64 + t];
        __syncthreads();
        const int a0 = t, a1 = t + 256;
        float acc0 = 0.f, acc1 = 0.f;
        const float* Wrow = Wdec + (size_t)(seg * 64) * A_;
#pragma unroll 8
        for (int h = 0; h < 64; ++h) {
            const float s = dhl[h];
            acc0 += s * Wrow[h * A_ + a0];
            acc1 += s * Wrow[h * A_ + a1];
        }
        if (seg == 0) { acc0 += bdec[a0]; acc1 += bdec[a1]; }
        dp[(size_t)(seg * B_ + b) * A_ + a0] = acc0;
        dp[(size_t)(seg * B_ + b) * A_ + a1] = acc1;
    }
}

// ---------------------------------------------------------------------------
// Fused kernel: bf16x2-split MFMA GEMM (128 x 512 x 1024 per block) +
// tanh score + masked softmax partials + ctx partials.
// Pipelined: W[kt+1] glds-staged while MFMAs consume W[kt] from REGISTERS;
// A double-buffered in LDS with global prefetch. All long-latency ops land
// one iteration ahead of use -> barriers are cheap.
// ---------------------------------------------------------------------------
__global__ __launch_bounds__(512, 2)
void fused_kernel(const float* __restrict__ enc,     // [B,S,E] fp32
                  const int*   __restrict__ masks,   // [B,S]
                  const bf16*  __restrict__ Whi_g,   // [A,E] bf16 (W^T hi)
                  const bf16*  __restrict__ Wlo_g,   // [A,E] bf16 (W^T lo)
                  const float* __restrict__ benc,    // [A]
                  const float* __restrict__ Watt,    // [A]
                  const float* __restrict__ batt,    // [1]
                  const float* __restrict__ dp,      // [8,B,A] dec_att parts
                  float* __restrict__ pm,            // [B*NCH]
                  float* __restrict__ pl,            // [B*NCH]
                  float* __restrict__ pctx) {        // [B*NCH, A]
    __shared__ union {
        struct {
            __align__(16) bf16 Whi[A_ * KT];          // 32 KB, frag-order
            __align__(16) bf16 Wlo[A_ * KT];          // 32 KB
            __align__(16) bf16 Ab[2][2][MB * KT];     // 32 KB dbuf [buf][hi/lo]
        } k;
        struct {
            float decl[A_], wattl[A_], bencl[A_];     // 6 KB
            float red[MB * 8];                        // 4 KB
            float score[MB], p[MB];                   // 1 KB
            int   mask[MB];                           // 0.5 KB
        } e;
    } sm;                                             // 96 KB total

    const int t    = threadIdx.x;
    const int wv   = t >> 6;      // wave 0..7
    const int L    = t & 63;      // lane
    const int quad = L >> 4;      // 0..3
    const int colL = L & 15;      // 0..15
    const int b    = blockIdx.x >> 4;
    const int ch   = blockIdx.x & 15;
    const int s0   = ch * MB;

    const float* encB = enc + ((size_t)(b * S_ + s0)) * E_;

    f32x4 acc[8][4];
#pragma unroll
    for (int mt = 0; mt < 8; ++mt)
#pragma unroll
        for (int nt = 0; nt < 4; ++nt) acc[mt][nt] = (f32x4){0.f, 0.f, 0.f, 0.f};

    // ---- A staging: thread t -> row t>>2, k-quad t&3 (8 consecutive k)
    const int arow = t >> 2;
    const int akq  = t & 3;
    const int a_wr = ((arow >> 4) * 512) + akq * 128 +
                     (((arow & 15) ^ (akq << 2)) * 8);     // swizzled elem off
    const float* aptr = encB + (size_t)arow * E_ + akq * 8;
    const int a_rd = quad * 128 + (((L & 15) ^ (quad << 2)) * 8);

    // ---- W stage helper values
    const size_t wg0 = (size_t)((wv * 4) * 16 + colL) * E_ + quad * 8;

    // ================= prologue: A[0] + W[0] =================
    float4 cA = *(const float4*)(aptr);
    float4 cB = *(const float4*)(aptr + 4);
#pragma unroll
    for (int i = 0; i < 4; ++i) {
        const int I = wv * 4 + i;
        const size_t goff = wg0 + (size_t)(i * 16) * E_;
        glds16(Whi_g + goff, &sm.k.Whi[I * 512]);
        glds16(Wlo_g + goff, &sm.k.Wlo[I * 512]);
    }
    {   // convert+write A[0] into buf 0
        const float xs[8] = {cA.x, cA.y, cA.z, cA.w, cB.x, cB.y, cB.z, cB.w};
        bf16x8 hv, lv;
#pragma unroll
        for (int j = 0; j < 8; ++j) {
            const bf16 h = (bf16)xs[j];
            hv[j] = h; lv[j] = (bf16)(xs[j] - (float)h);
        }
        *(bf16x8*)&sm.k.Ab[0][0][a_wr] = hv;
        *(bf16x8*)&sm.k.Ab[0][1][a_wr] = lv;
    }
    __syncthreads();   // drains own glds (vmcnt) + A writes -> W[0], A[0] ready

    bf16x8 bh[4], bl[4];
#pragma unroll
    for (int nt = 0; nt < 4; ++nt) {
        bh[nt] = *(const bf16x8*)&sm.k.Whi[(wv * 4 + nt) * 512 + L * 8];
        bl[nt] = *(const bf16x8*)&sm.k.Wlo[(wv * 4 + nt) * 512 + L * 8];
    }

    // ================= K loop =================
    for (int kt = 0; kt < NK; ++kt) {
        __syncthreads();   // B1: all waves hold W[kt] in regs; A[kt] visible
        const bool more = (kt + 1 < NK);
        if (more) {
            // stage W[kt+1] into LDS (consumed at end of this iter)
            const size_t kadd = (size_t)(kt + 1) * KT;
#pragma unroll
            for (int i = 0; i < 4; ++i) {
                const int I = wv * 4 + i;
                const size_t goff = wg0 + (size_t)(i * 16) * E_ + kadd;
                glds16(Whi_g + goff, &sm.k.Whi[I * 512]);
                glds16(Wlo_g + goff, &sm.k.Wlo[I * 512]);
            }
            // prefetch A[kt+1] fp32
            const float* np = aptr + (size_t)(kt + 1) * KT;
            cA = *(const float4*)(np);
            cB = *(const float4*)(np + 4);
        }

        // ---- MFMA block on W[kt] (regs) x A[kt] (LDS buf kt&1)
        const bf16* Ahi = sm.k.Ab[kt & 1][0];
        const bf16* Alo = sm.k.Ab[kt & 1][1];
#pragma unroll
        for (int mt = 0; mt < 8; ++mt) {
            const bf16x8 ah = *(const bf16x8*)&Ahi[mt * 512 + a_rd];
            const bf16x8 al = *(const bf16x8*)&Alo[mt * 512 + a_rd];
#pragma unroll
            for (int nt = 0; nt < 4; ++nt) {
                acc[mt][nt] = __builtin_amdgcn_mfma_f32_16x16x32_bf16(ah, bh[nt], acc[mt][nt], 0, 0, 0);
                acc[mt][nt] = __builtin_amdgcn_mfma_f32_16x16x32_bf16(al, bh[nt], acc[mt][nt], 0, 0, 0);
                acc[mt][nt] = __builtin_amdgcn_mfma_f32_16x16x32_bf16(ah, bl[nt], acc[mt][nt], 0, 0, 0);
            }
        }

        if (more) {
            // convert+write A[kt+1] into the other buffer
            const float xs[8] = {cA.x, cA.y, cA.z, cA.w, cB.x, cB.y, cB.z, cB.w};
            bf16x8 hv, lv;
#pragma unroll
            for (int j = 0; j < 8; ++j) {
                const bf16 h = (bf16)xs[j];
                hv[j] = h; lv[j] = (bf16)(xs[j] - (float)h);
            }
            *(bf16x8*)&sm.k.Ab[(kt + 1) & 1][0][a_wr] = hv;
            *(bf16x8*)&sm.k.Ab[(kt + 1) & 1][1][a_wr] = lv;
        }

        __syncthreads();   // B2: own glds drained (hidden under MFMAs); A[kt+1] visible
        if (more) {
#pragma unroll
            for (int nt = 0; nt < 4; ++nt) {
                bh[nt] = *(const bf16x8*)&sm.k.Whi[(wv * 4 + nt) * 512 + L * 8];
                bl[nt] = *(const bf16x8*)&sm.k.Wlo[(wv * 4 + nt) * 512 + L * 8];
            }
        }
    }

    // ================= epilogue =================
    // (last B2 guarantees all waves finished K-loop LDS reads)
    {
        float d = 0.f;
#pragma unroll
        for (int g = 0; g < 8; ++g) d += dp[(size_t)(g * B_ + b) * A_ + t];
        sm.e.decl[t]  = d;                 // t < 512 == A_
        sm.e.wattl[t] = Watt[t];
        sm.e.bencl[t] = benc[t];
        if (t < MB) sm.e.mask[t] = masks[(size_t)b * S_ + s0 + t];
    }
    __syncthreads();

    float sp[8][4];
#pragma unroll
    for (int mt = 0; mt < 8; ++mt)
#pragma unroll
        for (int r = 0; r < 4; ++r) sp[mt][r] = 0.f;

#pragma unroll
    for (int nt = 0; nt < 4; ++nt) {
        const int cg = wv * 64 + nt * 16 + colL;
        const float bv  = sm.e.bencl[cg];
        const float dv  = sm.e.decl[cg];
        const float wav = sm.e.wattl[cg];
#pragma unroll
        for (int mt = 0; mt < 8; ++mt)
#pragma unroll
            for (int r = 0; r < 4; ++r) {
                const float ea = acc[mt][nt][r] + bv;
                acc[mt][nt][r] = ea;
                sp[mt][r] += fast_tanh(ea + dv) * wav;
            }
    }
#pragma unroll
    for (int d = 1; d < 16; d <<= 1)
#pragma unroll
        for (int mt = 0; mt < 8; ++mt)
#pragma unroll
            for (int r = 0; r < 4; ++r)
                sp[mt][r] += __shfl_xor(sp[mt][r], d);
    if (colL == 0) {
#pragma unroll
        for (int mt = 0; mt < 8; ++mt)
#pragma unroll
            for (int r = 0; r < 4; ++r)
                sm.e.red[(mt * 16 + quad * 4 + r) * 8 + wv] = sp[mt][r];
    }
    __syncthreads();

    if (t < MB) {
        float s = 0.f;
#pragma unroll
        for (int j = 0; j < 8; ++j) s += sm.e.red[t * 8 + j];
        sm.e.score[t] = s + batt[0];
    }
    __syncthreads();

    float m_loc = -1e30f;
    for (int r = 0; r < MB; ++r)
        if (!sm.e.mask[r]) m_loc = fmaxf(m_loc, sm.e.score[r]);
    if (t < MB) sm.e.p[t] = sm.e.mask[t] ? 0.f : __expf(sm.e.score[t] - m_loc);
    __syncthreads();

    float ctxl[4] = {0.f, 0.f, 0.f, 0.f};
#pragma unroll
    for (int mt = 0; mt < 8; ++mt)
#pragma unroll
        for (int r = 0; r < 4; ++r) {
            const float p = sm.e.p[mt * 16 + quad * 4 + r];
#pragma unroll
            for (int nt = 0; nt < 4; ++nt) ctxl[nt] += p * acc[mt][nt][r];
        }
#pragma unroll
    for (int nt = 0; nt < 4; ++nt) {
        ctxl[nt] += __shfl_xor(ctxl[nt], 16);
        ctxl[nt] += __shfl_xor(ctxl[nt], 32);
    }
    if (quad == 0) {
#pragma unroll
        for (int nt = 0; nt < 4; ++nt)
            pctx[(size_t)blockIdx.x * A_ + wv * 64 + nt * 16 + colL] = ctxl[nt];
    }
    if (t == 0) {
        float l = 0.f;
        for (int r = 0; r < MB; ++r) l += sm.e.p[r];
        pm[blockIdx.x] = m_loc;
        pl[blockIdx.x] = l;
    }
}

// ---------------------------------------------------------------------------
// Combine: merge NCH chunk partials per batch row
// ---------------------------------------------------------------------------
__global__ __launch_bounds__(512)
void combine_kernel(const float* __restrict__ pm,
                    const float* __restrict__ pl,
                    const float* __restrict__ pctx,
                    float* __restrict__ out) {
    const int b = blockIdx.x;
    const int t = threadIdx.x;
    float m_g = -1e30f;
    for (int c = 0; c < NCH; ++c) m_g = fmaxf(m_g, pm[b * NCH + c]);
    float L = 0.f;
    for (int c = 0; c < NCH; ++c)
        L += pl[b * NCH + c] * __expf(pm[b * NCH + c] - m_g);
    const float inv = 1.f / L;
    float s = 0.f;
    for (int c = 0; c < NCH; ++c)
        s += pctx[((size_t)b * NCH + c) * A_ + t] * __expf(pm[b * NCH + c] - m_g);
    out[b * A_ + t] = s * inv;
}

// ---------------------------------------------------------------------------
extern "C" void kernel_launch(void* const* d_in, const int* in_sizes, int n_in,
                              void* d_out, int out_size, void* d_ws, size_t ws_size,
                              hipStream_t stream) {
    const float* enc  = (const float*)d_in[0];   // [B,S,2H] fp32
    const float* dh   = (const float*)d_in[1];   // [B,H]
    const int*   mks  = (const int*)  d_in[2];   // [B,S,1] bool->int
    const float* Wenc = (const float*)d_in[3];   // [2H,A]
    const float* benc = (const float*)d_in[4];   // [A]
    const float* Wdec = (const float*)d_in[5];   // [H,A]
    const float* bdec = (const float*)d_in[6];   // [A]
    const float* Watt = (const float*)d_in[7];   // [A]
    const float* batt = (const float*)d_in[8];   // [1]
    float* out = (float*)d_out;

    float* ws   = (float*)d_ws;
    float* pm   = ws;                             // 512 f
    float* pl   = pm + B_ * NCH;                  // 512 f
    float* pctx = pl + B_ * NCH;                  // 262144 f
    float* dp   = pctx + (size_t)B_ * NCH * A_;   // 131072 f
    bf16*  Whi  = (bf16*)(dp + 8 * B_ * A_);      // 1 MB
    bf16*  Wlo  = Whi + (size_t)A_ * E_;          // 1 MB
    (void)in_sizes; (void)n_in; (void)out_size; (void)ws_size;

    prep_kernel<<<384, 256, 0, stream>>>(Wenc, dh, Wdec, bdec, Whi, Wlo, dp);
    fused_kernel<<<B_ * NCH, 512, 0, stream>>>(
        enc, mks, Whi, Wlo, benc, Watt, batt, dp, pm, pl, pctx);
    combine_kernel<<<B_, 512, 0, stream>>>(pm, pl, pctx, out);
}